// Round 7
// baseline (134.939 us; speedup 1.0000x reference)
//
#include <hip/hip_runtime.h>
#include <hip/hip_bf16.h>
#include <math.h>

// Problem constants
#define NN 96
#define SS 4096
#define PP 4096
#define PH 1024
#define PHH 512
#define TP 3267            // TOTAL_PARAMS
#define KC_SPLIT 16
#define KCHUNK 256         // 4096 / 16

typedef short short8 __attribute__((ext_vector_type(8)));   // MFMA A/B frag (8 bf16)
typedef float float4v __attribute__((ext_vector_type(4)));  // MFMA C/D frag
typedef unsigned short ushort4v __attribute__((ext_vector_type(4)));

__device__ __forceinline__ float stp(float x) {
    float sp = (x > 15.0f) ? x : log1pf(expf(x));
    return sp * (1.0f / 6.0f);
}

__device__ __forceinline__ float sin_w0(float x) {
    // sin(30*x) via Cody-Waite reduction to revolutions + v_sin_f32
    constexpr double Cd = 30.0 / 6.283185307179586476925286766559;
    constexpr float C_hi = (float)Cd;
    constexpr float C_lo = (float)(Cd - (double)C_hi);
    float t = x * C_hi;
    float k = rintf(t);
    float r = fmaf(x, C_hi, -k);
    r = fmaf(x, C_lo, r);
    return __builtin_amdgcn_sinf(r);
}

// bf16 round-to-nearest-even helpers (bit ops; values finite)
__device__ __forceinline__ unsigned short f2bf(float f) {
    unsigned u = __float_as_uint(f);
    unsigned r = u + 0x7fffu + ((u >> 16) & 1u);
    return (unsigned short)(r >> 16);
}
__device__ __forceinline__ float bf2f(unsigned short b) {
    return __uint_as_float(((unsigned)b) << 16);
}
// split v into hi+lo bf16, pack into u32 (hi in upper half)
__device__ __forceinline__ unsigned splitpack(float v) {
    unsigned short hb = f2bf(v);
    unsigned short lb = f2bf(v - bf2f(hb));
    return (((unsigned)hb) << 16) | (unsigned)lb;
}

// ---------------- Kernel 1: build z, split into bf16 hi/lo planes ----------------
__global__ __launch_bounds__(256) void z_kernel(
    const float* __restrict__ loc, const float* __restrict__ log_scale,
    const float* __restrict__ h_loc, const float* __restrict__ h_ls,
    const float* __restrict__ hh_loc, const float* __restrict__ hh_ls,
    const float* __restrict__ eps, const float* __restrict__ h_eps,
    const float* __restrict__ hh_eps,
    const int* __restrict__ h_gi, const int* __restrict__ hh_gi,
    unsigned short* __restrict__ z_hi, unsigned short* __restrict__ z_lo)
{
    int t = blockIdx.x * 256 + threadIdx.x;      // t < 96*4096
    int p = t & (PP - 1);
    int n = t >> 12;
    int idx = n * PP + p;
    float s = loc[idx] + eps[idx] * stp(log_scale[idx]);
    int g  = h_gi[p];
    int gh = (n >> 4) * PH + g;
    float hs = h_loc[gh] + h_eps[gh] * stp(h_ls[gh]);
    int gg = hh_gi[p];
    float hhs = hh_loc[gg] + hh_eps[gg] * stp(hh_ls[gg]);
    float z = s + hs + hhs;
    unsigned short hb = f2bf(z);
    z_hi[idx] = hb;
    z_lo[idx] = f2bf(z - bf2f(hb));
}

// ---------------- Kernel 2: split-bf16 MFMA GEMM partials ----------------
// grid: 832 = 52 jt * 16 kc, 256 threads (4 waves, 16 cols each).
// Per k-step of 32: W loaded fp32 + split on the fly (each element exactly
// once globally); A read as prebuilt bf16 hi/lo planes. 3 MFMAs x 6 m-tiles.
#define MT(ACC, mt)                                                       \
    {                                                                     \
        const unsigned short* zh = z_hi + (size_t)((mt)*16 + e) * PP + kb + q4; \
        const unsigned short* zl = z_lo + (size_t)((mt)*16 + e) * PP + kb + q4; \
        ushort4v a0 = *(const ushort4v*)zh;                               \
        ushort4v a1 = *(const ushort4v*)(zh + 16);                        \
        ushort4v l0 = *(const ushort4v*)zl;                               \
        ushort4v l1 = *(const ushort4v*)(zl + 16);                        \
        short8 Ah = {(short)a0.x,(short)a0.y,(short)a0.z,(short)a0.w,     \
                     (short)a1.x,(short)a1.y,(short)a1.z,(short)a1.w};    \
        short8 Al = {(short)l0.x,(short)l0.y,(short)l0.z,(short)l0.w,     \
                     (short)l1.x,(short)l1.y,(short)l1.z,(short)l1.w};    \
        ACC = __builtin_amdgcn_mfma_f32_16x16x32_bf16(Ah, Bh, ACC, 0, 0, 0); \
        ACC = __builtin_amdgcn_mfma_f32_16x16x32_bf16(Al, Bh, ACC, 0, 0, 0); \
        ACC = __builtin_amdgcn_mfma_f32_16x16x32_bf16(Ah, Bl, ACC, 0, 0, 0); \
    }

__global__ __launch_bounds__(256, 4) void gemm_kernel(
    const float* __restrict__ Wm, const unsigned short* __restrict__ z_hi,
    const unsigned short* __restrict__ z_lo, float* __restrict__ partials)
{
    int b  = blockIdx.x;
    int kc = b & 15;
    int jt = b >> 4;
    int wave = threadIdx.x >> 6;
    int lane = threadIdx.x & 63;
    int e  = lane & 15;
    int q4 = (lane >> 4) << 2;
    int j  = jt * 64 + wave * 16 + e;        // output col
    int jc = j < TP ? j : TP - 1;            // clamped (loads stay in bounds)
    int k0 = kc * KCHUNK;

    float4v acc0 = {0,0,0,0}, acc1 = {0,0,0,0}, acc2 = {0,0,0,0};
    float4v acc3 = {0,0,0,0}, acc4 = {0,0,0,0}, acc5 = {0,0,0,0};

#pragma unroll 2
    for (int ks = 0; ks < KCHUNK / 32; ++ks) {
        int kb = k0 + ks * 32;
        // load W fp32 frag + split
        float bw[8];
#pragma unroll
        for (int i = 0; i < 8; ++i) {
            int k = kb + ((i >> 2) << 4) + q4 + (i & 3);
            bw[i] = Wm[(size_t)k * TP + jc];
        }
        short8 Bh, Bl;
#pragma unroll
        for (int i = 0; i < 8; ++i) {
            unsigned short hb = f2bf(bw[i]);
            Bh[i] = (short)hb;
            Bl[i] = (short)f2bf(bw[i] - bf2f(hb));
        }
        MT(acc0, 0) MT(acc1, 1) MT(acc2, 2)
        MT(acc3, 3) MT(acc4, 4) MT(acc5, 5)
    }

    if (j < TP) {
        float* pp = partials + (size_t)(kc * NN) * TP + j;
#pragma unroll
        for (int r = 0; r < 4; ++r) pp[(size_t)(q4 + r) * TP]      = acc0[r];
#pragma unroll
        for (int r = 0; r < 4; ++r) pp[(size_t)(16 + q4 + r) * TP] = acc1[r];
#pragma unroll
        for (int r = 0; r < 4; ++r) pp[(size_t)(32 + q4 + r) * TP] = acc2[r];
#pragma unroll
        for (int r = 0; r < 4; ++r) pp[(size_t)(48 + q4 + r) * TP] = acc3[r];
#pragma unroll
        for (int r = 0; r < 4; ++r) pp[(size_t)(64 + q4 + r) * TP] = acc4[r];
#pragma unroll
        for (int r = 0; r < 4; ++r) pp[(size_t)(80 + q4 + r) * TP] = acc5[r];
    }
}

// ---------------- Kernel 3: reduce partials + bias ----------------
__global__ __launch_bounds__(256) void reduce_kernel(
    const float* __restrict__ partials, const float* __restrict__ b_map,
    float* __restrict__ params)
{
    int t = blockIdx.x * 256 + threadIdx.x;
    if (t >= NN * TP) return;
    int j = t % TP;
    int n = t / TP;
    float a = b_map[j];
#pragma unroll
    for (int kc = 0; kc < KC_SPLIT; ++kc)
        a += partials[((size_t)(kc * NN + n)) * TP + j];
    params[(size_t)n * TP + j] = a;
}

// ---------------- Kernel 4: SIREN MLP, split-bf16 MFMA, 2-tile pipeline ----------
// Two 16-point tiles per wave in flight: tile1's MFMAs+sin fill tile0's LDS
// round-trip latency; one lgkmcnt drain per layer. All frags named (rule #20).
#define TSTRIDE 18

#define PRELOAD_HALF(lp, off, BH, BL)                                   \
    {                                                                   \
        _Pragma("unroll")                                               \
        for (int i = 0; i < 8; ++i) {                                   \
            int k = ((i >> 2) << 4) + q4 + (i & 3);                     \
            float w = (lp)[32 + k * 32 + e + (off)];                    \
            unsigned short hb = f2bf(w);                                \
            BH[i] = (short)hb;                                          \
            BL[i] = (short)f2bf(w - bf2f(hb));                          \
        }                                                               \
    }

#define LOADX(M0, AH, AL)                                               \
    {                                                                   \
        const float* xr = x + ((size_t)(n * SS + (M0) + e)) * 32;       \
        float4 xa = *(const float4*)(xr + q4);                          \
        float4 xb = *(const float4*)(xr + 16 + q4);                     \
        float xv[8] = {xa.x, xa.y, xa.z, xa.w, xb.x, xb.y, xb.z, xb.w}; \
        _Pragma("unroll")                                               \
        for (int i = 0; i < 8; ++i) {                                   \
            unsigned short hb = f2bf(xv[i]);                            \
            AH[i] = (short)hb;                                          \
            AL[i] = (short)f2bf(xv[i] - bf2f(hb));                      \
        }                                                               \
    }

// one hidden layer for BOTH tiles: 12 MFMAs, sin/split, one LDS drain
#define LAYER2(BH0, BL0, BH1, BL1, B0, B1)                              \
    {                                                                   \
        float4v pa0 = (float4v){B0, B0, B0, B0};                        \
        float4v pa1 = (float4v){B1, B1, B1, B1};                        \
        float4v pb0 = (float4v){B0, B0, B0, B0};                        \
        float4v pb1 = (float4v){B1, B1, B1, B1};                        \
        pa0 = __builtin_amdgcn_mfma_f32_16x16x32_bf16(Ahi, BH0, pa0, 0, 0, 0); \
        pb0 = __builtin_amdgcn_mfma_f32_16x16x32_bf16(Chi, BH0, pb0, 0, 0, 0); \
        pa0 = __builtin_amdgcn_mfma_f32_16x16x32_bf16(Alo, BH0, pa0, 0, 0, 0); \
        pb0 = __builtin_amdgcn_mfma_f32_16x16x32_bf16(Clo, BH0, pb0, 0, 0, 0); \
        pa0 = __builtin_amdgcn_mfma_f32_16x16x32_bf16(Ahi, BL0, pa0, 0, 0, 0); \
        pb0 = __builtin_amdgcn_mfma_f32_16x16x32_bf16(Chi, BL0, pb0, 0, 0, 0); \
        pa1 = __builtin_amdgcn_mfma_f32_16x16x32_bf16(Ahi, BH1, pa1, 0, 0, 0); \
        pb1 = __builtin_amdgcn_mfma_f32_16x16x32_bf16(Chi, BH1, pb1, 0, 0, 0); \
        pa1 = __builtin_amdgcn_mfma_f32_16x16x32_bf16(Alo, BH1, pa1, 0, 0, 0); \
        pb1 = __builtin_amdgcn_mfma_f32_16x16x32_bf16(Clo, BH1, pb1, 0, 0, 0); \
        pa1 = __builtin_amdgcn_mfma_f32_16x16x32_bf16(Ahi, BL1, pa1, 0, 0, 0); \
        pb1 = __builtin_amdgcn_mfma_f32_16x16x32_bf16(Chi, BL1, pb1, 0, 0, 0); \
        unsigned k0 = splitpack(sin_w0(pa0[0]));                        \
        unsigned k1 = splitpack(sin_w0(pa0[1]));                        \
        unsigned k2 = splitpack(sin_w0(pa0[2]));                        \
        unsigned k3 = splitpack(sin_w0(pa0[3]));                        \
        unsigned k4 = splitpack(sin_w0(pa1[0]));                        \
        unsigned k5 = splitpack(sin_w0(pa1[1]));                        \
        unsigned k6 = splitpack(sin_w0(pa1[2]));                        \
        unsigned k7 = splitpack(sin_w0(pa1[3]));                        \
        *(uint2*)(tpA + e * TSTRIDE + q4)            = make_uint2(k0, k1); \
        *(uint2*)(tpA + e * TSTRIDE + q4 + 2)        = make_uint2(k2, k3); \
        *(uint2*)(tpA + (e + 16) * TSTRIDE + q4)     = make_uint2(k4, k5); \
        *(uint2*)(tpA + (e + 16) * TSTRIDE + q4 + 2) = make_uint2(k6, k7); \
        unsigned m0_ = splitpack(sin_w0(pb0[0]));                       \
        unsigned m1_ = splitpack(sin_w0(pb0[1]));                       \
        unsigned m2_ = splitpack(sin_w0(pb0[2]));                       \
        unsigned m3_ = splitpack(sin_w0(pb0[3]));                       \
        unsigned m4_ = splitpack(sin_w0(pb1[0]));                       \
        unsigned m5_ = splitpack(sin_w0(pb1[1]));                       \
        unsigned m6_ = splitpack(sin_w0(pb1[2]));                       \
        unsigned m7_ = splitpack(sin_w0(pb1[3]));                       \
        *(uint2*)(tpB + e * TSTRIDE + q4)            = make_uint2(m0_, m1_); \
        *(uint2*)(tpB + e * TSTRIDE + q4 + 2)        = make_uint2(m2_, m3_); \
        *(uint2*)(tpB + (e + 16) * TSTRIDE + q4)     = make_uint2(m4_, m5_); \
        *(uint2*)(tpB + (e + 16) * TSTRIDE + q4 + 2) = make_uint2(m6_, m7_); \
        asm volatile("s_waitcnt lgkmcnt(0)" ::: "memory");              \
        __builtin_amdgcn_sched_barrier(0);                              \
        _Pragma("unroll")                                               \
        for (int i = 0; i < 8; ++i) {                                   \
            int k = ((i >> 2) << 4) + q4 + (i & 3);                     \
            unsigned u = tpA[k * TSTRIDE + e];                          \
            Ahi[i] = (short)(u >> 16);                                  \
            Alo[i] = (short)(u & 0xffffu);                              \
            unsigned v = tpB[k * TSTRIDE + e];                          \
            Chi[i] = (short)(v >> 16);                                  \
            Clo[i] = (short)(v & 0xffffu);                              \
        }                                                               \
    }

__global__ __launch_bounds__(256, 3) void mlp_kernel(
    const float* __restrict__ x, const float* __restrict__ params,
    float* __restrict__ out)
{
    int b = blockIdx.x;
    int n = b >> 4;
    int chunk = b & 15;
    int tid = threadIdx.x;
    int wave = tid >> 6;
    int lane = tid & 63;
    int e  = lane & 15;
    int q4 = (lane >> 4) << 2;

    __shared__ unsigned tiles[4][2][32 * TSTRIDE];
    unsigned* tpA = tiles[wave][0];
    unsigned* tpB = tiles[wave][1];

    const float* pr = params + (size_t)n * TP;

    // ---- preload ALL weights as named VGPR frags, once per block ----
    short8 B0h0, B0l0, B0h1, B0l1;
    short8 B1h0, B1l0, B1h1, B1l1;
    short8 B2h0, B2l0, B2h1, B2l1;
    short8 BFh, BFl;
    float b0_0, b0_1, b1_0, b1_1, b2_0, b2_1, bF;

    { const float* lp = pr;            b0_0 = lp[e]; b0_1 = lp[e + 16];
      PRELOAD_HALF(lp, 0, B0h0, B0l0)  PRELOAD_HALF(lp, 16, B0h1, B0l1) }
    { const float* lp = pr + 1056;     b1_0 = lp[e]; b1_1 = lp[e + 16];
      PRELOAD_HALF(lp, 0, B1h0, B1l0)  PRELOAD_HALF(lp, 16, B1h1, B1l1) }
    { const float* lp = pr + 2112;     b2_0 = lp[e]; b2_1 = lp[e + 16];
      PRELOAD_HALF(lp, 0, B2h0, B2l0)  PRELOAD_HALF(lp, 16, B2h1, B2l1) }
    {
        const float* lpf = pr + 3168;
        bF = (e < 3) ? lpf[e] : 0.0f;
#pragma unroll
        for (int i = 0; i < 8; ++i) {
            int k = ((i >> 2) << 4) + q4 + (i & 3);
            float w = (e < 3) ? lpf[3 + k * 3 + e] : 0.0f;
            unsigned short hb = f2bf(w);
            BFh[i] = (short)hb;
            BFl[i] = (short)f2bf(w - bf2f(hb));
        }
    }

    int p0 = chunk * 256 + wave * 64;

#pragma unroll 1
    for (int it = 0; it < 2; ++it) {
        int m0 = p0 + it * 32;     // tile0 rows m0.., tile1 rows m0+16..

        short8 Ahi, Alo, Chi, Clo;
        LOADX(m0, Ahi, Alo)
        LOADX(m0 + 16, Chi, Clo)

        LAYER2(B0h0, B0l0, B0h1, B0l1, b0_0, b0_1)
        LAYER2(B1h0, B1l0, B1h1, B1l1, b1_0, b1_1)
        LAYER2(B2h0, B2l0, B2h1, B2l1, b2_0, b2_1)

        // ---- final layer 32 -> 3, both tiles ----
        float4v fA = (float4v){bF, bF, bF, bF};
        float4v fB = (float4v){bF, bF, bF, bF};
        fA = __builtin_amdgcn_mfma_f32_16x16x32_bf16(Ahi, BFh, fA, 0, 0, 0);
        fB = __builtin_amdgcn_mfma_f32_16x16x32_bf16(Chi, BFh, fB, 0, 0, 0);
        fA = __builtin_amdgcn_mfma_f32_16x16x32_bf16(Alo, BFh, fA, 0, 0, 0);
        fB = __builtin_amdgcn_mfma_f32_16x16x32_bf16(Clo, BFh, fB, 0, 0, 0);
        fA = __builtin_amdgcn_mfma_f32_16x16x32_bf16(Ahi, BFl, fA, 0, 0, 0);
        fB = __builtin_amdgcn_mfma_f32_16x16x32_bf16(Chi, BFl, fB, 0, 0, 0);

        if (e < 3) {
#pragma unroll
            for (int r = 0; r < 4; ++r)
                out[((size_t)n * SS + m0 + q4 + r) * 3 + e] = fA[r];
#pragma unroll
            for (int r = 0; r < 4; ++r)
                out[((size_t)n * SS + m0 + 16 + q4 + r) * 3 + e] = fB[r];
        }
    }
}

extern "C" void kernel_launch(void* const* d_in, const int* in_sizes, int n_in,
                              void* d_out, int out_size, void* d_ws, size_t ws_size,
                              hipStream_t stream)
{
    const float* x        = (const float*)d_in[0];
    const float* loc      = (const float*)d_in[1];
    const float* log_sc   = (const float*)d_in[2];
    const float* h_loc    = (const float*)d_in[3];
    const float* h_ls     = (const float*)d_in[4];
    const float* hh_loc   = (const float*)d_in[5];
    const float* hh_ls    = (const float*)d_in[6];
    const float* eps      = (const float*)d_in[7];
    const float* h_eps    = (const float*)d_in[8];
    const float* hh_eps   = (const float*)d_in[9];
    const float* W_map    = (const float*)d_in[10];
    const float* b_map    = (const float*)d_in[11];
    const int*   h_gi     = (const int*)d_in[12];
    const int*   hh_gi    = (const int*)d_in[13];
    float* out = (float*)d_out;

    // workspace layout
    unsigned short* z_hi = (unsigned short*)d_ws;             // 96*4096 u16
    unsigned short* z_lo = z_hi + (size_t)NN * PP;            // 96*4096 u16
    float* partials = (float*)(z_lo + (size_t)NN * PP);       // 16*96*3267 f32
    float* params   = partials + (size_t)KC_SPLIT * NN * TP;  // 96*3267 f32

    z_kernel<<<(NN * PP) / 256, 256, 0, stream>>>(
        loc, log_sc, h_loc, h_ls, hh_loc, hh_ls, eps, h_eps, hh_eps,
        h_gi, hh_gi, z_hi, z_lo);

    gemm_kernel<<<52 * 16, 256, 0, stream>>>(W_map, z_hi, z_lo, partials);

    reduce_kernel<<<(NN * TP + 255) / 256, 256, 0, stream>>>(partials, b_map, params);

    mlp_kernel<<<96 * 16, 256, 0, stream>>>(x, params, out);
}

// Round 8
// 64.325 us; speedup vs baseline: 2.0978x; 2.0978x over previous
//
#include <hip/hip_runtime.h>
#include <hip/hip_bf16.h>
#include <math.h>

// Problem constants
#define NN 96
#define SS 4096
#define PP 4096
#define PH 1024
#define PHH 512
#define TP 3267            // TOTAL_PARAMS
#define KC_SPLIT 16
#define KCHUNK 256         // 4096 / 16
#define WSTR 68            // W LDS row stride (floats): 4*68 mod 32 = 16 -> 2-way
#define ZSTR 100           // z LDS row stride (u32):   4*100 mod 32 = 16 -> 2-way

typedef short short8 __attribute__((ext_vector_type(8)));   // MFMA A/B frag (8 bf16)
typedef float float4v __attribute__((ext_vector_type(4)));  // MFMA C/D frag

__device__ __forceinline__ float stp(float x) {
    float sp = (x > 15.0f) ? x : log1pf(expf(x));
    return sp * (1.0f / 6.0f);
}

__device__ __forceinline__ float sin_w0(float x) {
    // sin(30*x) via Cody-Waite reduction to revolutions + v_sin_f32
    constexpr double Cd = 30.0 / 6.283185307179586476925286766559;
    constexpr float C_hi = (float)Cd;
    constexpr float C_lo = (float)(Cd - (double)C_hi);
    float t = x * C_hi;
    float k = rintf(t);
    float r = fmaf(x, C_hi, -k);
    r = fmaf(x, C_lo, r);
    return __builtin_amdgcn_sinf(r);
}

// bf16 round-to-nearest-even helpers (bit ops; values finite)
__device__ __forceinline__ unsigned short f2bf(float f) {
    unsigned u = __float_as_uint(f);
    unsigned r = u + 0x7fffu + ((u >> 16) & 1u);
    return (unsigned short)(r >> 16);
}
__device__ __forceinline__ float bf2f(unsigned short b) {
    return __uint_as_float(((unsigned)b) << 16);
}
// split v into hi+lo bf16, pack into u32 (hi in upper half)
__device__ __forceinline__ unsigned splitpack(float v) {
    unsigned short hb = f2bf(v);
    unsigned short lb = f2bf(v - bf2f(hb));
    return (((unsigned)hb) << 16) | (unsigned)lb;
}

// ---------------- Kernel 1: build z, pack hi|lo bf16 into u32 plane ----------------
__global__ __launch_bounds__(256) void z_kernel(
    const float* __restrict__ loc, const float* __restrict__ log_scale,
    const float* __restrict__ h_loc, const float* __restrict__ h_ls,
    const float* __restrict__ hh_loc, const float* __restrict__ hh_ls,
    const float* __restrict__ eps, const float* __restrict__ h_eps,
    const float* __restrict__ hh_eps,
    const int* __restrict__ h_gi, const int* __restrict__ hh_gi,
    unsigned* __restrict__ z32)
{
    int t = blockIdx.x * 256 + threadIdx.x;      // t < 96*4096
    int p = t & (PP - 1);
    int n = t >> 12;
    int idx = n * PP + p;
    float s = loc[idx] + eps[idx] * stp(log_scale[idx]);
    int g  = h_gi[p];
    int gh = (n >> 4) * PH + g;
    float hs = h_loc[gh] + h_eps[gh] * stp(h_ls[gh]);
    int gg = hh_gi[p];
    float hhs = hh_loc[gg] + hh_eps[gg] * stp(hh_ls[gg]);
    z32[idx] = splitpack(s + hs + hhs);
}

// ---------------- Kernel 2: LDS-staged split-bf16 MFMA GEMM partials ----------------
// grid: 832 = 52 jt * 16 kc, block 256 (4 waves). Block output: 96 x 64.
// Per 32-k-step: W tile (32x64 f32) and z tile (transposed, 32k x 96m u32)
// staged via registers into padded LDS; frag reads are uniform 2-way (free).
#define MT(ACC, mt)                                                       \
    {                                                                     \
        short8 Ah, Al;                                                    \
        _Pragma("unroll")                                                 \
        for (int i = 0; i < 8; ++i) {                                     \
            int kl = ((i >> 2) << 4) + q4 + (i & 3);                      \
            unsigned u = zt[kl * ZSTR + (mt) * 16 + e];                   \
            Ah[i] = (short)(u >> 16);                                     \
            Al[i] = (short)(u & 0xffffu);                                 \
        }                                                                 \
        ACC = __builtin_amdgcn_mfma_f32_16x16x32_bf16(Ah, Bh, ACC, 0, 0, 0); \
        ACC = __builtin_amdgcn_mfma_f32_16x16x32_bf16(Al, Bh, ACC, 0, 0, 0); \
        ACC = __builtin_amdgcn_mfma_f32_16x16x32_bf16(Ah, Bl, ACC, 0, 0, 0); \
    }

__global__ __launch_bounds__(256, 3) void gemm_kernel(
    const float* __restrict__ Wm, const unsigned* __restrict__ z32,
    float* __restrict__ partials)
{
    int b  = blockIdx.x;
    int kc = b & 15;
    int jt = b >> 4;
    int tid = threadIdx.x;
    int wave = tid >> 6;
    int lane = tid & 63;
    int e  = lane & 15;
    int q4 = (lane >> 4) << 2;
    int j0 = (jt < 51) ? jt * 64 : (TP - 64);   // last block overlaps (identical writes)
    int j  = j0 + wave * 16 + e;
    int k0 = kc * KCHUNK;

    __shared__ float    wt[32 * WSTR];   // 8.7 KB
    __shared__ unsigned zt[32 * ZSTR];   // 12.8 KB

    float4v acc0 = {0,0,0,0}, acc1 = {0,0,0,0}, acc2 = {0,0,0,0};
    float4v acc3 = {0,0,0,0}, acc4 = {0,0,0,0}, acc5 = {0,0,0,0};

    // staging roles (constant per thread)
    int wrow = tid >> 3, wcol = tid & 7;          // W: 32 rows x 8 threads
    int sm   = tid >> 1, skh = (tid & 1) << 4;    // z: 96 rows x 2 threads (tid<192)

#pragma unroll 1
    for (int ks = 0; ks < KCHUNK / 32; ++ks) {
        int kb = k0 + ks * 32;

        // ---- global -> regs (issued before barrier; latency overlaps prev compute) ----
        float wv[8];
        const float* wsrc = Wm + (size_t)(kb + wrow) * TP + j0 + wcol;
#pragma unroll
        for (int u = 0; u < 8; ++u) wv[u] = wsrc[u * 8];
        unsigned zv[16];
        if (tid < 192) {
            const unsigned* zsrc = z32 + (size_t)sm * PP + kb + skh;
#pragma unroll
            for (int u = 0; u < 4; ++u)
                *(uint4*)(zv + u * 4) = *(const uint4*)(zsrc + u * 4);
        }

        __syncthreads();   // previous k-step's reads complete

        // ---- regs -> LDS ----
#pragma unroll
        for (int u = 0; u < 8; ++u) wt[wrow * WSTR + wcol + u * 8] = wv[u];
        if (tid < 192) {
#pragma unroll
            for (int kk = 0; kk < 16; ++kk) zt[(skh + kk) * ZSTR + sm] = zv[kk];
        }

        __syncthreads();   // staging visible

        // ---- B frag: W column (wave*16+e), split on the fly ----
        short8 Bh, Bl;
#pragma unroll
        for (int i = 0; i < 8; ++i) {
            int kl = ((i >> 2) << 4) + q4 + (i & 3);
            float w = wt[kl * WSTR + wave * 16 + e];
            unsigned short hb = f2bf(w);
            Bh[i] = (short)hb;
            Bl[i] = (short)f2bf(w - bf2f(hb));
        }

        MT(acc0, 0) MT(acc1, 1) MT(acc2, 2)
        MT(acc3, 3) MT(acc4, 4) MT(acc5, 5)
    }

    float* pp = partials + (size_t)(kc * NN) * TP + j;
#pragma unroll
    for (int r = 0; r < 4; ++r) pp[(size_t)(q4 + r) * TP]      = acc0[r];
#pragma unroll
    for (int r = 0; r < 4; ++r) pp[(size_t)(16 + q4 + r) * TP] = acc1[r];
#pragma unroll
    for (int r = 0; r < 4; ++r) pp[(size_t)(32 + q4 + r) * TP] = acc2[r];
#pragma unroll
    for (int r = 0; r < 4; ++r) pp[(size_t)(48 + q4 + r) * TP] = acc3[r];
#pragma unroll
    for (int r = 0; r < 4; ++r) pp[(size_t)(64 + q4 + r) * TP] = acc4[r];
#pragma unroll
    for (int r = 0; r < 4; ++r) pp[(size_t)(80 + q4 + r) * TP] = acc5[r];
}

// ---------------- Kernel 3: reduce partials + bias ----------------
__global__ __launch_bounds__(256) void reduce_kernel(
    const float* __restrict__ partials, const float* __restrict__ b_map,
    float* __restrict__ params)
{
    int t = blockIdx.x * 256 + threadIdx.x;
    if (t >= NN * TP) return;
    int j = t % TP;
    int n = t / TP;
    float a = b_map[j];
#pragma unroll
    for (int kc = 0; kc < KC_SPLIT; ++kc)
        a += partials[((size_t)(kc * NN + n)) * TP + j];
    params[(size_t)n * TP + j] = a;
}

// ---------------- Kernel 4: SIREN MLP, split-bf16 MFMA, 2-tile pipeline ----------
#define TSTRIDE 18

#define PRELOAD_HALF(lp, off, BH, BL)                                   \
    {                                                                   \
        _Pragma("unroll")                                               \
        for (int i = 0; i < 8; ++i) {                                   \
            int k = ((i >> 2) << 4) + q4 + (i & 3);                     \
            float w = (lp)[32 + k * 32 + e + (off)];                    \
            unsigned short hb = f2bf(w);                                \
            BH[i] = (short)hb;                                          \
            BL[i] = (short)f2bf(w - bf2f(hb));                          \
        }                                                               \
    }

#define LOADX(M0, AH, AL)                                               \
    {                                                                   \
        const float* xr = x + ((size_t)(n * SS + (M0) + e)) * 32;       \
        float4 xa = *(const float4*)(xr + q4);                          \
        float4 xb = *(const float4*)(xr + 16 + q4);                     \
        float xv[8] = {xa.x, xa.y, xa.z, xa.w, xb.x, xb.y, xb.z, xb.w}; \
        _Pragma("unroll")                                               \
        for (int i = 0; i < 8; ++i) {                                   \
            unsigned short hb = f2bf(xv[i]);                            \
            AH[i] = (short)hb;                                          \
            AL[i] = (short)f2bf(xv[i] - bf2f(hb));                      \
        }                                                               \
    }

// one hidden layer for BOTH tiles: 12 MFMAs, sin/split, one LDS drain
#define LAYER2(BH0, BL0, BH1, BL1, B0, B1)                              \
    {                                                                   \
        float4v pa0 = (float4v){B0, B0, B0, B0};                        \
        float4v pa1 = (float4v){B1, B1, B1, B1};                        \
        float4v pb0 = (float4v){B0, B0, B0, B0};                        \
        float4v pb1 = (float4v){B1, B1, B1, B1};                        \
        pa0 = __builtin_amdgcn_mfma_f32_16x16x32_bf16(Ahi, BH0, pa0, 0, 0, 0); \
        pb0 = __builtin_amdgcn_mfma_f32_16x16x32_bf16(Chi, BH0, pb0, 0, 0, 0); \
        pa0 = __builtin_amdgcn_mfma_f32_16x16x32_bf16(Alo, BH0, pa0, 0, 0, 0); \
        pb0 = __builtin_amdgcn_mfma_f32_16x16x32_bf16(Clo, BH0, pb0, 0, 0, 0); \
        pa0 = __builtin_amdgcn_mfma_f32_16x16x32_bf16(Ahi, BL0, pa0, 0, 0, 0); \
        pb0 = __builtin_amdgcn_mfma_f32_16x16x32_bf16(Chi, BL0, pb0, 0, 0, 0); \
        pa1 = __builtin_amdgcn_mfma_f32_16x16x32_bf16(Ahi, BH1, pa1, 0, 0, 0); \
        pb1 = __builtin_amdgcn_mfma_f32_16x16x32_bf16(Chi, BH1, pb1, 0, 0, 0); \
        pa1 = __builtin_amdgcn_mfma_f32_16x16x32_bf16(Alo, BH1, pa1, 0, 0, 0); \
        pb1 = __builtin_amdgcn_mfma_f32_16x16x32_bf16(Clo, BH1, pb1, 0, 0, 0); \
        pa1 = __builtin_amdgcn_mfma_f32_16x16x32_bf16(Ahi, BL1, pa1, 0, 0, 0); \
        pb1 = __builtin_amdgcn_mfma_f32_16x16x32_bf16(Chi, BL1, pb1, 0, 0, 0); \
        unsigned k0 = splitpack(sin_w0(pa0[0]));                        \
        unsigned k1 = splitpack(sin_w0(pa0[1]));                        \
        unsigned k2 = splitpack(sin_w0(pa0[2]));                        \
        unsigned k3 = splitpack(sin_w0(pa0[3]));                        \
        unsigned k4 = splitpack(sin_w0(pa1[0]));                        \
        unsigned k5 = splitpack(sin_w0(pa1[1]));                        \
        unsigned k6 = splitpack(sin_w0(pa1[2]));                        \
        unsigned k7 = splitpack(sin_w0(pa1[3]));                        \
        *(uint2*)(tpA + e * TSTRIDE + q4)            = make_uint2(k0, k1); \
        *(uint2*)(tpA + e * TSTRIDE + q4 + 2)        = make_uint2(k2, k3); \
        *(uint2*)(tpA + (e + 16) * TSTRIDE + q4)     = make_uint2(k4, k5); \
        *(uint2*)(tpA + (e + 16) * TSTRIDE + q4 + 2) = make_uint2(k6, k7); \
        unsigned m0_ = splitpack(sin_w0(pb0[0]));                       \
        unsigned m1_ = splitpack(sin_w0(pb0[1]));                       \
        unsigned m2_ = splitpack(sin_w0(pb0[2]));                       \
        unsigned m3_ = splitpack(sin_w0(pb0[3]));                       \
        unsigned m4_ = splitpack(sin_w0(pb1[0]));                       \
        unsigned m5_ = splitpack(sin_w0(pb1[1]));                       \
        unsigned m6_ = splitpack(sin_w0(pb1[2]));                       \
        unsigned m7_ = splitpack(sin_w0(pb1[3]));                       \
        *(uint2*)(tpB + e * TSTRIDE + q4)            = make_uint2(m0_, m1_); \
        *(uint2*)(tpB + e * TSTRIDE + q4 + 2)        = make_uint2(m2_, m3_); \
        *(uint2*)(tpB + (e + 16) * TSTRIDE + q4)     = make_uint2(m4_, m5_); \
        *(uint2*)(tpB + (e + 16) * TSTRIDE + q4 + 2) = make_uint2(m6_, m7_); \
        asm volatile("s_waitcnt lgkmcnt(0)" ::: "memory");              \
        __builtin_amdgcn_sched_barrier(0);                              \
        _Pragma("unroll")                                               \
        for (int i = 0; i < 8; ++i) {                                   \
            int k = ((i >> 2) << 4) + q4 + (i & 3);                     \
            unsigned u = tpA[k * TSTRIDE + e];                          \
            Ahi[i] = (short)(u >> 16);                                  \
            Alo[i] = (short)(u & 0xffffu);                              \
            unsigned v = tpB[k * TSTRIDE + e];                          \
            Chi[i] = (short)(v >> 16);                                  \
            Clo[i] = (short)(v & 0xffffu);                              \
        }                                                               \
    }

__global__ __launch_bounds__(256, 3) void mlp_kernel(
    const float* __restrict__ x, const float* __restrict__ params,
    float* __restrict__ out)
{
    int b = blockIdx.x;
    int n = b >> 4;
    int chunk = b & 15;
    int tid = threadIdx.x;
    int wave = tid >> 6;
    int lane = tid & 63;
    int e  = lane & 15;
    int q4 = (lane >> 4) << 2;

    __shared__ unsigned tiles[4][2][32 * TSTRIDE];
    unsigned* tpA = tiles[wave][0];
    unsigned* tpB = tiles[wave][1];

    const float* pr = params + (size_t)n * TP;

    short8 B0h0, B0l0, B0h1, B0l1;
    short8 B1h0, B1l0, B1h1, B1l1;
    short8 B2h0, B2l0, B2h1, B2l1;
    short8 BFh, BFl;
    float b0_0, b0_1, b1_0, b1_1, b2_0, b2_1, bF;

    { const float* lp = pr;            b0_0 = lp[e]; b0_1 = lp[e + 16];
      PRELOAD_HALF(lp, 0, B0h0, B0l0)  PRELOAD_HALF(lp, 16, B0h1, B0l1) }
    { const float* lp = pr + 1056;     b1_0 = lp[e]; b1_1 = lp[e + 16];
      PRELOAD_HALF(lp, 0, B1h0, B1l0)  PRELOAD_HALF(lp, 16, B1h1, B1l1) }
    { const float* lp = pr + 2112;     b2_0 = lp[e]; b2_1 = lp[e + 16];
      PRELOAD_HALF(lp, 0, B2h0, B2l0)  PRELOAD_HALF(lp, 16, B2h1, B2l1) }
    {
        const float* lpf = pr + 3168;
        bF = (e < 3) ? lpf[e] : 0.0f;
#pragma unroll
        for (int i = 0; i < 8; ++i) {
            int k = ((i >> 2) << 4) + q4 + (i & 3);
            float w = (e < 3) ? lpf[3 + k * 3 + e] : 0.0f;
            unsigned short hb = f2bf(w);
            BFh[i] = (short)hb;
            BFl[i] = (short)f2bf(w - bf2f(hb));
        }
    }

    int p0 = chunk * 256 + wave * 64;

#pragma unroll 1
    for (int it = 0; it < 2; ++it) {
        int m0 = p0 + it * 32;

        short8 Ahi, Alo, Chi, Clo;
        LOADX(m0, Ahi, Alo)
        LOADX(m0 + 16, Chi, Clo)

        LAYER2(B0h0, B0l0, B0h1, B0l1, b0_0, b0_1)
        LAYER2(B1h0, B1l0, B1h1, B1l1, b1_0, b1_1)
        LAYER2(B2h0, B2l0, B2h1, B2l1, b2_0, b2_1)

        float4v fA = (float4v){bF, bF, bF, bF};
        float4v fB = (float4v){bF, bF, bF, bF};
        fA = __builtin_amdgcn_mfma_f32_16x16x32_bf16(Ahi, BFh, fA, 0, 0, 0);
        fB = __builtin_amdgcn_mfma_f32_16x16x32_bf16(Chi, BFh, fB, 0, 0, 0);
        fA = __builtin_amdgcn_mfma_f32_16x16x32_bf16(Alo, BFh, fA, 0, 0, 0);
        fB = __builtin_amdgcn_mfma_f32_16x16x32_bf16(Clo, BFh, fB, 0, 0, 0);
        fA = __builtin_amdgcn_mfma_f32_16x16x32_bf16(Ahi, BFl, fA, 0, 0, 0);
        fB = __builtin_amdgcn_mfma_f32_16x16x32_bf16(Chi, BFl, fB, 0, 0, 0);

        if (e < 3) {
#pragma unroll
            for (int r = 0; r < 4; ++r)
                out[((size_t)n * SS + m0 + q4 + r) * 3 + e] = fA[r];
#pragma unroll
            for (int r = 0; r < 4; ++r)
                out[((size_t)n * SS + m0 + 16 + q4 + r) * 3 + e] = fB[r];
        }
    }
}

extern "C" void kernel_launch(void* const* d_in, const int* in_sizes, int n_in,
                              void* d_out, int out_size, void* d_ws, size_t ws_size,
                              hipStream_t stream)
{
    const float* x        = (const float*)d_in[0];
    const float* loc      = (const float*)d_in[1];
    const float* log_sc   = (const float*)d_in[2];
    const float* h_loc    = (const float*)d_in[3];
    const float* h_ls     = (const float*)d_in[4];
    const float* hh_loc   = (const float*)d_in[5];
    const float* hh_ls    = (const float*)d_in[6];
    const float* eps      = (const float*)d_in[7];
    const float* h_eps    = (const float*)d_in[8];
    const float* hh_eps   = (const float*)d_in[9];
    const float* W_map    = (const float*)d_in[10];
    const float* b_map    = (const float*)d_in[11];
    const int*   h_gi     = (const int*)d_in[12];
    const int*   hh_gi    = (const int*)d_in[13];
    float* out = (float*)d_out;

    // workspace layout
    unsigned* z32  = (unsigned*)d_ws;                        // 96*4096 u32
    float* partials = (float*)(z32 + (size_t)NN * PP);       // 16*96*3267 f32
    float* params   = partials + (size_t)KC_SPLIT * NN * TP; // 96*3267 f32

    z_kernel<<<(NN * PP) / 256, 256, 0, stream>>>(
        loc, log_sc, h_loc, h_ls, hh_loc, hh_ls, eps, h_eps, hh_eps,
        h_gi, hh_gi, z32);

    gemm_kernel<<<52 * 16, 256, 0, stream>>>(W_map, z32, partials);

    reduce_kernel<<<(NN * TP + 255) / 256, 256, 0, stream>>>(partials, b_map, params);

    mlp_kernel<<<96 * 16, 256, 0, stream>>>(x, params, out);
}